// Round 1
// baseline (281.911 us; speedup 1.0000x reference)
//
#include <hip/hip_runtime.h>
#include <hip/hip_bf16.h>

#define MM 256
#define KK 4096
#define NN 32000
#define BN 128
#define BK 64
#define NT (KK / BK)   // 64 K-steps
#define LDX 72         // padded LDS row stride in ushorts (144 B)
#define LDW 72

typedef __bf16 bf16x8 __attribute__((ext_vector_type(8)));
typedef float f32x4 __attribute__((ext_vector_type(4)));

__device__ __forceinline__ unsigned pk(float a, float b) {
    ushort lo = __builtin_bit_cast(ushort, __float2bfloat16(a));
    ushort hi = __builtin_bit_cast(ushort, __float2bfloat16(b));
    return (unsigned)lo | ((unsigned)hi << 16);
}

// x fp32 [256][4096] -> bf16 (as ushort) in ws
__global__ void cvt_x_kernel(const float* __restrict__ x, ushort* __restrict__ xb) {
    int i = (blockIdx.x * 256 + threadIdx.x) * 8;
    float4 a = *(const float4*)(x + i);
    float4 b = *(const float4*)(x + i + 4);
    uint4 p;
    p.x = pk(a.x, a.y); p.y = pk(a.z, a.w);
    p.z = pk(b.x, b.y); p.w = pk(b.z, b.w);
    *(uint4*)(xb + i) = p;
}

// C[m][n] = sum_k x[m][k] * w[n][k]; BM=256 (all M), BN=128, BK=64.
// 512 threads = 8 waves as 4(M) x 2(N); each wave owns 64x64 via 4x4 16x16x32 MFMA tiles.
template <bool XB>
__global__ __launch_bounds__(512, 2) void gemm_kernel(
    const ushort* __restrict__ xb, const float* __restrict__ xf,
    const float* __restrict__ w, float* __restrict__ out) {
    __shared__ ushort xs[MM * LDX];   // 36864 B
    __shared__ ushort wt[BN * LDW];   // 18432 B

    const int tid  = threadIdx.x;
    const int lane = tid & 63;
    const int wid  = tid >> 6;
    const int wm   = wid >> 1;   // 0..3
    const int wn   = wid & 1;    // 0..1
    const int n0   = blockIdx.x * BN;

    // x staging: 2048 16B-chunks (256 rows x 8 slots); thread t does chunks t+512*i
    const int xrow  = tid >> 3;   // 0..63, +64*i
    const int xslot = tid & 7;
    const int xoff  = xrow * KK + xslot * 8;          // element offset (x row-major)
    // W staging: thread t loads 16 consecutive fp32 of row t>>2
    const int wrow = tid >> 2;    // 0..127
    const int wqs  = tid & 3;
    const float* wbase = w + (size_t)(n0 + wrow) * KK + wqs * 16;

    f32x4 acc[4][4];
#pragma unroll
    for (int i = 0; i < 4; ++i)
#pragma unroll
        for (int j = 0; j < 4; ++j) acc[i][j] = f32x4{0.f, 0.f, 0.f, 0.f};

    auto issue = [&](int t, uint4 (&xr)[4], float4 (&xrf)[8], float4 (&wr)[4]) {
        const int ko = t * BK;
        if constexpr (XB) {
#pragma unroll
            for (int i = 0; i < 4; ++i)
                xr[i] = *(const uint4*)(xb + xoff + ko + i * 64 * KK);
        } else {
#pragma unroll
            for (int i = 0; i < 4; ++i) {
                xrf[2 * i]     = *(const float4*)(xf + xoff + ko + i * 64 * KK);
                xrf[2 * i + 1] = *(const float4*)(xf + xoff + ko + i * 64 * KK + 4);
            }
        }
#pragma unroll
        for (int i = 0; i < 4; ++i)
            wr[i] = *(const float4*)(wbase + ko + i * 4);
    };

    auto stage = [&](uint4 (&xr)[4], float4 (&xrf)[8], float4 (&wr)[4]) {
        if constexpr (XB) {
#pragma unroll
            for (int i = 0; i < 4; ++i)
                *(uint4*)&xs[(xrow + 64 * i) * LDX + xslot * 8] = xr[i];
        } else {
#pragma unroll
            for (int i = 0; i < 4; ++i) {
                uint4 p;
                p.x = pk(xrf[2 * i].x, xrf[2 * i].y);
                p.y = pk(xrf[2 * i].z, xrf[2 * i].w);
                p.z = pk(xrf[2 * i + 1].x, xrf[2 * i + 1].y);
                p.w = pk(xrf[2 * i + 1].z, xrf[2 * i + 1].w);
                *(uint4*)&xs[(xrow + 64 * i) * LDX + xslot * 8] = p;
            }
        }
        uint4 p0, p1;
        p0.x = pk(wr[0].x, wr[0].y); p0.y = pk(wr[0].z, wr[0].w);
        p0.z = pk(wr[1].x, wr[1].y); p0.w = pk(wr[1].z, wr[1].w);
        p1.x = pk(wr[2].x, wr[2].y); p1.y = pk(wr[2].z, wr[2].w);
        p1.z = pk(wr[3].x, wr[3].y); p1.w = pk(wr[3].z, wr[3].w);
        *(uint4*)&wt[wrow * LDW + wqs * 16]     = p0;
        *(uint4*)&wt[wrow * LDW + wqs * 16 + 8] = p1;
    };

    auto compute = [&]() {
#pragma unroll
        for (int kf = 0; kf < 2; ++kf) {
            const int ko = kf * 32 + (lane >> 4) * 8;
            uint4 af[4], bfr[4];
#pragma unroll
            for (int mi = 0; mi < 4; ++mi)
                af[mi] = *(const uint4*)&xs[(wm * 64 + mi * 16 + (lane & 15)) * LDX + ko];
#pragma unroll
            for (int ni = 0; ni < 4; ++ni)
                bfr[ni] = *(const uint4*)&wt[(wn * 64 + ni * 16 + (lane & 15)) * LDW + ko];
#pragma unroll
            for (int mi = 0; mi < 4; ++mi)
#pragma unroll
                for (int ni = 0; ni < 4; ++ni)
                    acc[mi][ni] = __builtin_amdgcn_mfma_f32_16x16x32_bf16(
                        __builtin_bit_cast(bf16x8, af[mi]),
                        __builtin_bit_cast(bf16x8, bfr[ni]), acc[mi][ni], 0, 0, 0);
        }
    };

    uint4 xA[4], xBr[4];
    float4 xfA[8], xfB[8];
    float4 wA[4], wB[4];

    issue(0, xA, xfA, wA);

#pragma unroll 1
    for (int t = 0; t < NT; t += 2) {
        // ---- even tile t ----
        __builtin_amdgcn_s_barrier();                       // prev reads done (dataflow), LDS free
        stage(xA, xfA, wA);                                 // compiler inserts vmcnt wait on regs
        __builtin_amdgcn_sched_barrier(0);
        asm volatile("s_waitcnt lgkmcnt(0)" ::: "memory");  // writes visible
        __builtin_amdgcn_s_barrier();
        if (t + 1 < NT) issue(t + 1, xBr, xfB, wB);         // overlap with compute
        compute();

        // ---- odd tile t+1 ----
        __builtin_amdgcn_s_barrier();
        stage(xBr, xfB, wB);
        __builtin_amdgcn_sched_barrier(0);
        asm volatile("s_waitcnt lgkmcnt(0)" ::: "memory");
        __builtin_amdgcn_s_barrier();
        if (t + 2 < NT) issue(t + 2, xA, xfA, wA);
        compute();
    }

    // epilogue: D layout per 16x16 tile: col = lane&15, row = (lane>>4)*4 + v
#pragma unroll
    for (int mi = 0; mi < 4; ++mi)
#pragma unroll
        for (int ni = 0; ni < 4; ++ni) {
            const int rowb = wm * 64 + mi * 16 + (lane >> 4) * 4;
            const int col  = n0 + wn * 64 + ni * 16 + (lane & 15);
#pragma unroll
            for (int v = 0; v < 4; ++v)
                out[(size_t)(rowb + v) * NN + col] = acc[mi][ni][v];
        }
}

extern "C" void kernel_launch(void* const* d_in, const int* in_sizes, int n_in,
                              void* d_out, int out_size, void* d_ws, size_t ws_size,
                              hipStream_t stream) {
    const float* x = (const float*)d_in[0];
    const float* w = (const float*)d_in[1];
    float* out = (float*)d_out;
    ushort* xb = (ushort*)d_ws;

    if (ws_size >= (size_t)MM * KK * sizeof(ushort)) {
        cvt_x_kernel<<<512, 256, 0, stream>>>(x, xb);
        gemm_kernel<true><<<NN / BN, 512, 0, stream>>>(xb, x, w, out);
    } else {
        gemm_kernel<false><<<NN / BN, 512, 0, stream>>>(nullptr, x, w, out);
    }
}

// Round 2
// 143.872 us; speedup vs baseline: 1.9595x; 1.9595x over previous
//
#include <hip/hip_runtime.h>
#include <hip/hip_bf16.h>

#define MM 256
#define KK 4096
#define NN 32000
#define BN 128
#define BK 64
#define NT (KK / BK)   // 64 K-steps

typedef __bf16 bf16x8 __attribute__((ext_vector_type(8)));
typedef float f32x4 __attribute__((ext_vector_type(4)));

__device__ __forceinline__ unsigned pk(float a, float b) {
    unsigned short lo = __builtin_bit_cast(unsigned short, __float2bfloat16(a));
    unsigned short hi = __builtin_bit_cast(unsigned short, __float2bfloat16(b));
    return (unsigned)lo | ((unsigned)hi << 16);
}

// x fp32 [256][4096] -> bf16 (as ushort) in ws
__global__ void cvt_x_kernel(const float* __restrict__ x, unsigned short* __restrict__ xb) {
    int i = (blockIdx.x * 256 + threadIdx.x) * 8;
    float4 a = *(const float4*)(x + i);
    float4 b = *(const float4*)(x + i + 4);
    uint4 p;
    p.x = pk(a.x, a.y); p.y = pk(a.z, a.w);
    p.z = pk(b.x, b.y); p.w = pk(b.z, b.w);
    *(uint4*)(xb + i) = p;
}

// C[m][n] = sum_k x[m][k] * w[n][k]; BM=256 (all M), BN=128, BK=64.
// 512 threads = 8 waves as 4(M) x 2(N); per-wave 64x64 via 4x4 16x16x32 MFMA.
// Depth-2 reg prefetch + counted vmcnt + LDS dbuf + 1 barrier/tile + XOR swizzle.
template <bool XB>
__global__ __launch_bounds__(512, 2) void gemm_kernel(
    const unsigned short* __restrict__ xb, const float* __restrict__ xf,
    const float* __restrict__ w, float* __restrict__ out) {
    __shared__ unsigned short xs[2][MM * 64];   // 2 x 32 KB, swizzled chunks
    __shared__ unsigned short wt[2][BN * 64];   // 2 x 16 KB, swizzled chunks

    const int tid  = threadIdx.x;
    const int lane = tid & 63;
    const int wid  = tid >> 6;
    const int wm   = wid >> 1;   // 0..3
    const int wn   = wid & 1;    // 0..1
    const int n0   = blockIdx.x * BN;
    const int l15  = lane & 15;
    const int lg   = lane >> 4;

    // x staging: thread handles rows xrow+64i, chunk xslot (8 ushorts)
    const int xrow  = tid >> 3;   // 0..63
    const int xslot = tid & 7;
    const int xgoff = xrow * KK + xslot * 8;
    const int xsoff = xrow * 64 + ((xslot ^ (xrow & 7)) * 8);

    // W staging: i -> row wid*16 + i*4 + lg, float col l15*4 (256B contiguous/row/instr)
    const float* wbase = w + (size_t)(n0 + wid * 16 + lg) * KK + l15 * 4;

    f32x4 acc[4][4];
#pragma unroll
    for (int i = 0; i < 4; ++i)
#pragma unroll
        for (int j = 0; j < 4; ++j) acc[i][j] = f32x4{0.f, 0.f, 0.f, 0.f};

    uint4  xA[4], xB2[4];
    float4 xfA[8], xfB[8];
    float4 wA[4], wB[4];

    auto issue = [&](int t, uint4 (&xr)[4], float4 (&xrf)[8], float4 (&wr)[4]) {
        const int ko = t * BK;
        if constexpr (XB) {
#pragma unroll
            for (int i = 0; i < 4; ++i)
                xr[i] = *(const uint4*)(xb + xgoff + ko + i * 64 * KK);
        } else {
#pragma unroll
            for (int i = 0; i < 4; ++i) {
                xrf[2 * i]     = *(const float4*)(xf + xgoff + ko + i * 64 * KK);
                xrf[2 * i + 1] = *(const float4*)(xf + xgoff + ko + i * 64 * KK + 4);
            }
        }
#pragma unroll
        for (int i = 0; i < 4; ++i)
            wr[i] = *(const float4*)(wbase + (size_t)i * 4 * KK + ko);
    };

    auto stage = [&](int p, uint4 (&xr)[4], float4 (&xrf)[8], float4 (&wr)[4]) {
#pragma unroll
        for (int i = 0; i < 4; ++i) {
            uint4 v;
            if constexpr (XB) {
                v = xr[i];
            } else {
                v.x = pk(xrf[2 * i].x, xrf[2 * i].y);
                v.y = pk(xrf[2 * i].z, xrf[2 * i].w);
                v.z = pk(xrf[2 * i + 1].x, xrf[2 * i + 1].y);
                v.w = pk(xrf[2 * i + 1].z, xrf[2 * i + 1].w);
            }
            *(uint4*)&xs[p][xsoff + i * 64 * 64] = v;
        }
#pragma unroll
        for (int i = 0; i < 4; ++i) {
            const int r  = wid * 16 + i * 4 + lg;
            const int c8 = l15 >> 1;
            uint2 d;
            d.x = pk(wr[i].x, wr[i].y);
            d.y = pk(wr[i].z, wr[i].w);
            *(uint2*)&wt[p][r * 64 + ((c8 ^ (r & 7)) * 8) + (l15 & 1) * 4] = d;
        }
    };

    auto compute = [&](int p) {
#pragma unroll
        for (int kf = 0; kf < 2; ++kf) {
            const int c8 = kf * 4 + lg;
            const int sw = (c8 ^ (lane & 7)) * 8;
            uint4 af[4], bfr[4];
#pragma unroll
            for (int mi = 0; mi < 4; ++mi)
                af[mi] = *(const uint4*)&xs[p][(wm * 64 + mi * 16 + l15) * 64 + sw];
#pragma unroll
            for (int ni = 0; ni < 4; ++ni)
                bfr[ni] = *(const uint4*)&wt[p][(wn * 64 + ni * 16 + l15) * 64 + sw];
#pragma unroll
            for (int mi = 0; mi < 4; ++mi)
#pragma unroll
                for (int ni = 0; ni < 4; ++ni)
                    acc[mi][ni] = __builtin_amdgcn_mfma_f32_16x16x32_bf16(
                        __builtin_bit_cast(bf16x8, af[mi]),
                        __builtin_bit_cast(bf16x8, bfr[ni]), acc[mi][ni], 0, 0, 0);
        }
    };

    issue(0, xA, xfA, wA);
    issue(1, xB2, xfB, wB);

#pragma unroll 1
    for (int t = 0; t < NT; t += 2) {
        // ---- even tile t: buffers A, LDS p=0 ----
        stage(0, xA, xfA, wA);              // compiler waits vmcnt(8): A oldest, B in flight
        if (t + 2 < NT) issue(t + 2, xA, xfA, wA);
        __builtin_amdgcn_sched_barrier(0);
        asm volatile("s_waitcnt lgkmcnt(0)" ::: "memory");
        __builtin_amdgcn_s_barrier();       // raw barrier: vmcnt NOT drained
        compute(0);

        // ---- odd tile t+1: buffers B, LDS p=1 ----
        stage(1, xB2, xfB, wB);
        if (t + 3 < NT) issue(t + 3, xB2, xfB, wB);
        __builtin_amdgcn_sched_barrier(0);
        asm volatile("s_waitcnt lgkmcnt(0)" ::: "memory");
        __builtin_amdgcn_s_barrier();
        compute(1);
    }

    // epilogue: D layout per 16x16 tile: col = lane&15, row = (lane>>4)*4 + v
#pragma unroll
    for (int mi = 0; mi < 4; ++mi)
#pragma unroll
        for (int ni = 0; ni < 4; ++ni) {
            const int rowb = wm * 64 + mi * 16 + lg * 4;
            const int col  = n0 + wn * 64 + ni * 16 + l15;
#pragma unroll
            for (int v = 0; v < 4; ++v)
                out[(size_t)(rowb + v) * NN + col] = acc[mi][ni][v];
        }
}

extern "C" void kernel_launch(void* const* d_in, const int* in_sizes, int n_in,
                              void* d_out, int out_size, void* d_ws, size_t ws_size,
                              hipStream_t stream) {
    const float* x = (const float*)d_in[0];
    const float* w = (const float*)d_in[1];
    float* out = (float*)d_out;
    unsigned short* xb = (unsigned short*)d_ws;

    if (ws_size >= (size_t)MM * KK * sizeof(unsigned short)) {
        cvt_x_kernel<<<512, 256, 0, stream>>>(x, xb);
        gemm_kernel<true><<<NN / BN, 512, 0, stream>>>(xb, x, w, out);
    } else {
        gemm_kernel<false><<<NN / BN, 512, 0, stream>>>(nullptr, x, w, out);
    }
}